// Round 18
// baseline (693.448 us; speedup 1.0000x reference)
//
#include <hip/hip_runtime.h>
#include <hip/hip_bf16.h>
#include <math.h>

#define BB 4
#define SEQ 2048
#define HEADS 16
#define DH 64
#define HID 1024
#define MM (BB*SEQ)
#define KK HID

typedef __attribute__((ext_vector_type(8))) short bf16x8;
typedef __attribute__((ext_vector_type(4))) float f32x4;
typedef __attribute__((ext_vector_type(16))) float f32x16;
typedef unsigned short u16;
typedef unsigned int u32;

__device__ __forceinline__ u16 f2bf(float f){
  u32 u = __builtin_bit_cast(u32, f);
  u += 0x7fffu + ((u>>16)&1u);
  return (u16)(u>>16);
}

// 8x f32 -> packed bf16, integer RNE form (R12-proven)
__device__ __forceinline__ uint4 pack8(const float4 a, const float4 b){
  uint4 r;
  r.x = (u32)f2bf(a.x) | ((u32)f2bf(a.y)<<16);
  r.y = (u32)f2bf(a.z) | ((u32)f2bf(a.w)<<16);
  r.z = (u32)f2bf(b.x) | ((u32)f2bf(b.y)<<16);
  r.w = (u32)f2bf(b.z) | ((u32)f2bf(b.w)<<16);
  return r;
}

#define MFMA(a,b,c)   __builtin_amdgcn_mfma_f32_16x16x32_bf16(a,b,c,0,0,0)
#define MFMA32(a,b,c) __builtin_amdgcn_mfma_f32_32x32x16_bf16(a,b,c,0,0,0)

// ---------------- RoPE cos/sin table: [pos][p] float2, p = 0..31 -------------
__global__ void rope_tab_kernel(float2* tab){
  int idx = blockIdx.x*256 + threadIdx.x;
  if (idx >= SEQ*32) return;
  int pos = idx >> 5, p = idx & 31;
  double inv = exp2(-(double)p * (13.287712379549449/32.0)); // 10000^(-p/32)
  double a = (double)pos * inv;
  tab[idx] = make_float2((float)cos(a), (float)sin(a));
}

// ---------------- padding-mask normalizer (int32 or uint8 robust) ------------
__global__ __launch_bounds__(1024)
void mask_bias_kernel(const int* pm, float* bias, u32* flagbits, int nelem){
  __shared__ int flag;
  if (threadIdx.x == 0) flag = 0;
  if (threadIdx.x < BB) flagbits[threadIdx.x] = 0u;
  __syncthreads();
  int bad = 0;
  for (int i = threadIdx.x; i < nelem/4; i += 1024){
    u32 v = ((const u32*)pm)[i];
    if (v > 1u) bad = 1;
  }
  if (bad) atomicOr(&flag, 1);
  __syncthreads();
  const int u8mode = flag;
  for (int i = threadIdx.x; i < nelem; i += 1024){
    int v = u8mode ? (int)((const unsigned char*)pm)[i] : pm[i];
    bias[i] = v ? 0.f : -__builtin_inff();
    if (!v) atomicOr(&flagbits[i>>11], 1u << ((i & (SEQ-1)) >> 6));
  }
}

// ---------------- fused QKV GEMM (R16 structure, 6 blocks/CU) ----------------
// blockIdx.z: 0 -> Q (RoPE + 0.125*log2e, scatter b,h,n,d)
//             1 -> K (RoPE, scatter b,h,n,d)
//             2 -> V (plain, TRANSPOSED store b,h,d,n)
__global__ __launch_bounds__(256,6)
void qkv_k(const float* xq, const float* xk, const float* xv,
           const float* Wq, const float* Wk, const float* Wv,
           u16* qo, u16* ko, u16* vo, const float2* tab)
{
  constexpr int BK = 32;
  __shared__ u16 lA[128][40];
  __shared__ u16 lB[128][40];
  const int tid  = threadIdx.x;
  const int lane = tid & 63;
  const int wid  = tid >> 6;
  const int wr = wid >> 1, wc = wid & 1;
  const int bm = blockIdx.x, bn = blockIdx.y;
  const int z  = blockIdx.z;           // wave-uniform mode
  const int arow0 = bm*128, brow0 = bn*128;

  const float* Af = (z==0) ? xq : (z==1) ? xk : xv;
  const float* W  = (z==0) ? Wq : (z==1) ? Wk : Wv;

  f32x4 acc[4][4];
  #pragma unroll
  for (int i=0;i<4;i++)
    #pragma unroll
    for (int j=0;j<4;j++) acc[i][j] = (f32x4){0.f,0.f,0.f,0.f};

  const int sr = tid >> 2;
  const int sc = tid & 3;

  float4 ra[2][2], rb[2][2];

  auto loadA = [&](int k0){
    #pragma unroll
    for (int s=0;s<2;s++){
      const float* p = Af + (size_t)(arow0 + sr + s*64)*KK + k0 + sc*8;
      ra[s][0] = *(const float4*)p;
      ra[s][1] = *(const float4*)(p+4);
    }
  };
  auto loadB = [&](int k0){
    #pragma unroll
    for (int s=0;s<2;s++){
      const float* p = W + (size_t)(brow0 + sr + s*64)*KK + k0 + sc*8;
      rb[s][0] = *(const float4*)p;
      rb[s][1] = *(const float4*)(p+4);
    }
  };

  loadA(0); loadB(0);

  for (int t=0; t<KK/BK; ++t){
    __syncthreads();
    *(uint4*)&lA[sr   ][sc*8] = pack8(ra[0][0], ra[0][1]);
    *(uint4*)&lA[sr+64][sc*8] = pack8(ra[1][0], ra[1][1]);
    *(uint4*)&lB[sr   ][sc*8] = pack8(rb[0][0], rb[0][1]);
    *(uint4*)&lB[sr+64][sc*8] = pack8(rb[1][0], rb[1][1]);
    __syncthreads();
    if (t+1 < KK/BK){ loadA((t+1)*BK); loadB((t+1)*BK); }

    bf16x8 af[4], bfr[4];
    const int g = lane >> 4, rr = lane & 15;
    #pragma unroll
    for (int i=0;i<4;i++) af[i]  = *(const bf16x8*)&lA[wr*64 + i*16 + rr][g*8];
    #pragma unroll
    for (int j=0;j<4;j++) bfr[j] = *(const bf16x8*)&lB[wc*64 + j*16 + rr][g*8];
    #pragma unroll
    for (int i=0;i<4;i++)
      #pragma unroll
      for (int j=0;j<4;j++)
        acc[i][j] = MFMA(af[i], bfr[j], acc[i][j]);
  }

  // epilogue (wave-uniform branch on z)
  if (z == 2){
    #pragma unroll
    for (int i=0;i<4;i++){
      #pragma unroll
      for (int j=0;j<4;j++){
        const int m0 = arow0 + wr*64 + i*16 + (lane>>4)*4;
        const int c  = brow0 + wc*64 + j*16 + (lane&15);
        const int pos = m0 & (SEQ-1);
        const int bidx = m0 >> 11;
        const int h = c >> 6, dd = c & 63;
        uint2 pk;
        pk.x = (u32)f2bf(acc[i][j][0]) | ((u32)f2bf(acc[i][j][1])<<16);
        pk.y = (u32)f2bf(acc[i][j][2]) | ((u32)f2bf(acc[i][j][3])<<16);
        *(uint2*)&vo[((size_t)(bidx*HEADS + h)*DH + dd)*SEQ + pos] = pk;
      }
    }
  } else {
    u16* outp = (z==0) ? qo : ko;
    const float scl = (z==0) ? 0.18033688011112042f : 1.0f; // 0.125*log2(e)
    #pragma unroll
    for (int i=0;i<4;i++){
      #pragma unroll
      for (int j=0;j<4;j++){
        #pragma unroll
        for (int r=0;r<4;r++){
          const int m = arow0 + wr*64 + i*16 + (lane>>4)*4 + r;
          const int c = brow0 + wc*64 + j*16 + (lane&15);
          float v = acc[i][j][r];
          const int pos = m & (SEQ-1);
          const int bidx = m >> 11;
          const int h = c >> 6, dd = c & 63;
          float2 cs = tab[pos*32 + (dd>>1)];
          float vp = __shfl_xor(v, 1);
          float o = ((dd&1)==0) ? (v*cs.x - vp*cs.y) : (v*cs.x + vp*cs.y);
          o *= scl;
          outp[(((size_t)(bidx*HEADS + h))*SEQ + pos)*DH + dd] = f2bf(o);
        }
      }
    }
  }
}

// ---------------- out-projection GEMM (R16 structure, 6 blocks/CU) -----------
__global__ __launch_bounds__(256,6)
void gemm_out_k(const u16* Ab, const float* W, float* outp)
{
  constexpr int BK = 32;
  __shared__ u16 lA[128][40];
  __shared__ u16 lB[128][40];
  const int tid  = threadIdx.x;
  const int lane = tid & 63;
  const int wid  = tid >> 6;
  const int wr = wid >> 1, wc = wid & 1;
  const int bm = blockIdx.x, bn = blockIdx.y;
  const int arow0 = bm*128, brow0 = bn*128;

  f32x4 acc[4][4];
  #pragma unroll
  for (int i=0;i<4;i++)
    #pragma unroll
    for (int j=0;j<4;j++) acc[i][j] = (f32x4){0.f,0.f,0.f,0.f};

  const int sr = tid >> 2;
  const int sc = tid & 3;

  float4 rb[2][2];
  uint4  rab[2];

  auto loadA = [&](int k0){
    const u16* p = Ab + (size_t)(arow0 + (tid>>1))*KK + k0 + (tid&1)*16;
    rab[0] = *(const uint4*)(p);
    rab[1] = *(const uint4*)(p+8);
  };
  auto loadB = [&](int k0){
    #pragma unroll
    for (int s=0;s<2;s++){
      const float* p = W + (size_t)(brow0 + sr + s*64)*KK + k0 + sc*8;
      rb[s][0] = *(const float4*)p;
      rb[s][1] = *(const float4*)(p+4);
    }
  };

  loadA(0); loadB(0);

  for (int t=0; t<KK/BK; ++t){
    __syncthreads();
    *(uint4*)&lA[tid>>1][(tid&1)*16 + 0] = rab[0];
    *(uint4*)&lA[tid>>1][(tid&1)*16 + 8] = rab[1];
    *(uint4*)&lB[sr   ][sc*8] = pack8(rb[0][0], rb[0][1]);
    *(uint4*)&lB[sr+64][sc*8] = pack8(rb[1][0], rb[1][1]);
    __syncthreads();
    if (t+1 < KK/BK){ loadA((t+1)*BK); loadB((t+1)*BK); }

    bf16x8 af[4], bfr[4];
    const int g = lane >> 4, rr = lane & 15;
    #pragma unroll
    for (int i=0;i<4;i++) af[i]  = *(const bf16x8*)&lA[wr*64 + i*16 + rr][g*8];
    #pragma unroll
    for (int j=0;j<4;j++) bfr[j] = *(const bf16x8*)&lB[wc*64 + j*16 + rr][g*8];
    #pragma unroll
    for (int i=0;i<4;i++)
      #pragma unroll
      for (int j=0;j<4;j++)
        acc[i][j] = MFMA(af[i], bfr[j], acc[i][j]);
  }

  #pragma unroll
  for (int i=0;i<4;i++)
    #pragma unroll
    for (int j=0;j<4;j++)
      #pragma unroll
      for (int r=0;r<4;r++){
        const int m = arow0 + wr*64 + i*16 + (lane>>4)*4 + r;
        const int c = brow0 + wc*64 + j*16 + (lane&15);
        outp[(size_t)m*HID + c] = acc[i][j][r];
      }
}

// ---------------- flash attention (R12 structure, 4 blocks/CU) ---------------
__global__ __launch_bounds__(256,4)
void attn_k(const u16* q, const u16* kkp, const u16* vtp, u16* o,
            const float* bias_g, const u32* flagbits, const int* pcaus, const int* psp)
{
  const int tid = threadIdx.x, lane = tid & 63, wid = tid >> 6;
  const int NQT = SEQ/64;
  const int wg = blockIdx.x;
  const int xcd = wg & 7, kk2 = wg >> 3;
  const int bh = xcd*8 + (kk2 >> 4);
  const int qpair = kk2 & 15;
  const int q0lo = qpair*64;
  const int q0hi = (NQT-1-qpair)*64;
  const int b = bh >> 4;
  const int causal = *pcaus, sp = *psp;

  __shared__ u16 lK[2][64*64];
  __shared__ u16 lV[2][64*64];

  const size_t hbase = (size_t)bh * SEQ * DH;
  const int h = lane >> 5, ln31 = lane & 31, ln7 = lane & 7;

  const int i0w = (wid < 2) ? (q0lo + wid*32) : (q0hi + (wid-2)*32);
  const int myq = i0w + ln31;
  const u32 fbits = flagbits[b];

  bf16x8 qf[4];
  {
    const u16* qr = q + hbase + (size_t)myq*DH;
    #pragma unroll
    for (int s=0;s<4;s++) qf[s] = *(const bf16x8*)(qr + 16*s + 8*h);
  }

  int swz[4];
  #pragma unroll
  for (int s=0;s<4;s++) swz[s] = ((2*s + h) ^ ln7) * 8;

  f32x16 oac[2];
  #pragma unroll
  for (int t=0;t<16;t++){ oac[0][t] = 0.f; oac[1][t] = 0.f; }
  float mrun = -__builtin_inff(), lrun = 0.f;

  int jmax = causal ? ((q0hi+63 > sp-1) ? q0hi+63 : sp-1) : (SEQ-1);
  if (jmax > SEQ-1) jmax = SEQ-1;
  const int ntile = (jmax >> 6) + 1;

  uint4 kr0, kr1, vr0, vr1;
  const int srow = tid >> 2;
  const int sg   = (tid & 3)*2;
  const int sw   = srow & 7;
  auto gload = [&](int kt){
    const int j0 = kt*64;
    const u16* pk = kkp + hbase + (size_t)(j0+srow)*DH + sg*8;
    kr0 = *(const uint4*)pk;  kr1 = *(const uint4*)(pk+8);
    const u16* pv = vtp + hbase + (size_t)srow*SEQ + j0 + sg*8;
    vr0 = *(const uint4*)pv;  vr1 = *(const uint4*)(pv+8);
  };
  auto lwrite = [&](int buf){
    *(uint4*)&lK[buf][srow*64 + ((sg    ^sw)*8)] = kr0;
    *(uint4*)&lK[buf][srow*64 + (((sg+1)^sw)*8)] = kr1;
    *(uint4*)&lV[buf][srow*64 + ((sg    ^sw)*8)] = vr0;
    *(uint4*)&lV[buf][srow*64 + (((sg+1)^sw)*8)] = vr1;
  };

  gload(0);
  lwrite(0);
  int cur = 0;

  for (int kt=0; kt<ntile; ++kt){
    const int j0 = kt*64;
    __syncthreads();
    if (kt+1 < ntile) gload(kt+1);

    const bool active = !(causal && j0 >= sp && j0 > i0w+31);
    if (active){
      const u16* Kb = lK[cur];
      const u16* Vb = lV[cur];

      f32x16 sA, sB;
      #pragma unroll
      for (int t=0;t<16;t++){ sA[t] = 0.f; sB[t] = 0.f; }
      __builtin_amdgcn_s_setprio(1);
      #pragma unroll
      for (int s=0;s<4;s++){
        bf16x8 k0 = *(const bf16x8*)&Kb[ ln31    *64 + swz[s]];
        bf16x8 k1 = *(const bf16x8*)&Kb[(32+ln31)*64 + swz[s]];
        sA = MFMA32(k0, qf[s], sA);
        sB = MFMA32(k1, qf[s], sB);
      }
      __builtin_amdgcn_s_setprio(0);

      float sv[32];
      #pragma unroll
      for (int t=0;t<16;t++){ sv[t] = sA[t]; sv[16+t] = sB[t]; }

      if ((fbits >> kt) & 1u){
        #pragma unroll
        for (int t=0;t<32;t++){
          const int rt = ((t&3) + 8*((t&15)>>2) + 4*h) + 32*(t>>4);
          sv[t] += bias_g[b*SEQ + j0 + rt];
        }
      }
      const bool needmask = causal && !((j0+63 < sp) || (i0w >= sp && j0+63 <= i0w));
      if (needmask){
        #pragma unroll
        for (int t=0;t<32;t++){
          const int jj = j0 + ((t&3) + 8*((t&15)>>2) + 4*h) + 32*(t>>4);
          const bool allow = (jj < sp) || (myq >= sp && myq >= jj);
          sv[t] = allow ? sv[t] : -__builtin_inff();
        }
      }

      float m8[8];
      #pragma unroll
      for (int t=0;t<8;t++)
        m8[t] = fmaxf(fmaxf(sv[t], sv[t+8]), fmaxf(sv[t+16], sv[t+24]));
      float m4a = fmaxf(fmaxf(m8[0],m8[1]), fmaxf(m8[2],m8[3]));
      float m4b = fmaxf(fmaxf(m8[4],m8[5]), fmaxf(m8[6],m8[7]));
      float pmax = fmaxf(m4a, m4b);
      pmax = fmaxf(pmax, __shfl_xor(pmax, 32));
      const float mnew = fmaxf(mrun, pmax);
      if (!__all(pmax - mrun <= 8.f)){
        const float fac = exp2f(mrun - mnew);
        mrun = mnew;
        lrun *= fac;
        oac[0] *= fac;
        oac[1] *= fac;
      }
      float p[32];
      #pragma unroll
      for (int t=0;t<32;t++) p[t] = exp2f(sv[t] - mrun);
      float a16[16];
      #pragma unroll
      for (int t=0;t<16;t++) a16[t] = p[t] + p[t+16];
      float a8[8];
      #pragma unroll
      for (int t=0;t<8;t++) a8[t] = a16[t] + a16[t+8];
      float rs = ((a8[0]+a8[1]) + (a8[2]+a8[3])) + ((a8[4]+a8[5]) + (a8[6]+a8[7]));
      rs += __shfl_xor(rs, 32);
      lrun += rs;

      u32 w[16];
      #pragma unroll
      for (int u=0;u<16;u++){
        asm("v_cvt_pk_bf16_f32 %0, %1, %2" : "=v"(w[u]) : "v"(p[2*u]), "v"(p[2*u+1]));
      }

      __builtin_amdgcn_s_setprio(1);
      #pragma unroll
      for (int st=0; st<4; ++st){
        const int base = 8*(st>>1) + 4*(st&1);
        u32 x0 = h ? w[base+0] : w[base+2];
        u32 x1 = h ? w[base+1] : w[base+3];
        u32 r0 = (u32)__shfl_xor((int)x0, 32);
        u32 r1 = (u32)__shfl_xor((int)x1, 32);
        uint4 fw;
        fw.x = h ? r0 : w[base+0];
        fw.y = h ? r1 : w[base+1];
        fw.z = h ? w[base+2] : r0;
        fw.w = h ? w[base+3] : r1;
        bf16x8 pf = __builtin_bit_cast(bf16x8, fw);
        #pragma unroll
        for (int dt=0; dt<2; ++dt){
          bf16x8 vf = *(const bf16x8*)&Vb[(dt*32+ln31)*64 + swz[st]];
          oac[dt] = MFMA32(vf, pf, oac[dt]);
        }
      }
      __builtin_amdgcn_s_setprio(0);
    }

    if (kt+1 < ntile) lwrite(cur^1);
    cur ^= 1;
  }

  const float inv = 1.f / lrun;
  u16* orow = o + ((size_t)(b*SEQ) + myq)*HID + (size_t)(bh&15)*DH;
  #pragma unroll
  for (int dt=0; dt<2; ++dt)
    #pragma unroll
    for (int a=0; a<4; ++a){
      const int d0 = dt*32 + 8*a + 4*h;
      uint2 pk;
      pk.x = (u32)f2bf(oac[dt][4*a+0]*inv) | ((u32)f2bf(oac[dt][4*a+1]*inv)<<16);
      pk.y = (u32)f2bf(oac[dt][4*a+2]*inv) | ((u32)f2bf(oac[dt][4*a+3]*inv)<<16);
      *(uint2*)(orow + d0) = pk;
    }
}

// -----------------------------------------------------------------------------
extern "C" void kernel_launch(void* const* d_in, const int* in_sizes, int n_in,
                              void* d_out, int out_size, void* d_ws, size_t ws_size,
                              hipStream_t stream)
{
  const float* x_q = (const float*)d_in[0];
  const float* x_k = (const float*)d_in[1];
  const float* x_v = (const float*)d_in[2];
  const float* W_q = (const float*)d_in[3];
  const float* W_k = (const float*)d_in[4];
  const float* W_v = (const float*)d_in[5];
  const float* W_o = (const float*)d_in[6];
  const int*   pm  = (const int*)d_in[7];
  const int* caus = (const int*)d_in[8];
  const int* sp   = (const int*)d_in[9];

  char* ws = (char*)d_ws;
  float2* tab   = (float2*)ws;                      // 512 KiB
  u16*  v_ws    = (u16*)(ws + (1u<<20));            // 16 MiB (V^T: b,h,d,n)
  u16*  o_ws    = (u16*)(ws + (17u<<20));           // 16 MiB
  float* bias   = (float*)(ws + (33u<<20));         // 32 KiB
  u32*  flagb   = (u32*)(ws + (33u<<20) + (1u<<15));
  // q,k scratch live inside d_out (32 MiB); stream order makes this race-free
  // (structure proven passing in rounds 2-6, 11, 12, 14-17).
  u16* q_ws = (u16*)d_out;
  u16* k_ws = ((u16*)d_out) + (size_t)MM*HID;

  rope_tab_kernel<<<SEQ*32/256, 256, 0, stream>>>(tab);
  mask_bias_kernel<<<1, 1024, 0, stream>>>(pm, bias, flagb, BB*SEQ);

  dim3 gq(MM/128, HID/128, 3);
  qkv_k<<<gq, 256, 0, stream>>>(x_q, x_k, x_v, W_q, W_k, W_v,
                                q_ws, k_ws, v_ws, tab);

  attn_k<<<1024, 256, 0, stream>>>(q_ws, k_ws, v_ws, o_ws, bias, flagb, caus, sp);

  dim3 gg(MM/128, HID/128);
  gemm_out_k<<<gg, 256, 0, stream>>>(o_ws, W_o, (float*)d_out);
}

// Round 19
// 275.326 us; speedup vs baseline: 2.5186x; 2.5186x over previous
//
#include <hip/hip_runtime.h>
#include <hip/hip_bf16.h>
#include <math.h>

#define BB 4
#define SEQ 2048
#define HEADS 16
#define DH 64
#define HID 1024
#define MM (BB*SEQ)
#define KK HID

typedef __attribute__((ext_vector_type(8))) short bf16x8;
typedef __attribute__((ext_vector_type(4))) float f32x4;
typedef __attribute__((ext_vector_type(16))) float f32x16;
typedef unsigned short u16;
typedef unsigned int u32;

__device__ __forceinline__ u16 f2bf(float f){
  u32 u = __builtin_bit_cast(u32, f);
  u += 0x7fffu + ((u>>16)&1u);
  return (u16)(u>>16);
}

// 8x f32 -> packed bf16, integer RNE form (R12-proven)
__device__ __forceinline__ uint4 pack8(const float4 a, const float4 b){
  uint4 r;
  r.x = (u32)f2bf(a.x) | ((u32)f2bf(a.y)<<16);
  r.y = (u32)f2bf(a.z) | ((u32)f2bf(a.w)<<16);
  r.z = (u32)f2bf(b.x) | ((u32)f2bf(b.y)<<16);
  r.w = (u32)f2bf(b.z) | ((u32)f2bf(b.w)<<16);
  return r;
}

#define MFMA(a,b,c)   __builtin_amdgcn_mfma_f32_16x16x32_bf16(a,b,c,0,0,0)
#define MFMA32(a,b,c) __builtin_amdgcn_mfma_f32_32x32x16_bf16(a,b,c,0,0,0)

// ---------------- RoPE cos/sin table: [pos][p] float2, p = 0..31 -------------
__global__ void rope_tab_kernel(float2* tab){
  int idx = blockIdx.x*256 + threadIdx.x;
  if (idx >= SEQ*32) return;
  int pos = idx >> 5, p = idx & 31;
  double inv = exp2(-(double)p * (13.287712379549449/32.0)); // 10000^(-p/32)
  double a = (double)pos * inv;
  tab[idx] = make_float2((float)cos(a), (float)sin(a));
}

// ---------------- padding-mask normalizer (int32 or uint8 robust) ------------
__global__ __launch_bounds__(1024)
void mask_bias_kernel(const int* pm, float* bias, u32* flagbits, int nelem){
  __shared__ int flag;
  if (threadIdx.x == 0) flag = 0;
  if (threadIdx.x < BB) flagbits[threadIdx.x] = 0u;
  __syncthreads();
  int bad = 0;
  for (int i = threadIdx.x; i < nelem/4; i += 1024){
    u32 v = ((const u32*)pm)[i];
    if (v > 1u) bad = 1;
  }
  if (bad) atomicOr(&flag, 1);
  __syncthreads();
  const int u8mode = flag;
  for (int i = threadIdx.x; i < nelem; i += 1024){
    int v = u8mode ? (int)((const unsigned char*)pm)[i] : pm[i];
    bias[i] = v ? 0.f : -__builtin_inff();
    if (!v) atomicOr(&flagbits[i>>11], 1u << ((i & (SEQ-1)) >> 6));
  }
}

// ---------------- fused QKV GEMM (R17-proven: 4 blocks/CU) -------------------
// blockIdx.z: 0 -> Q (RoPE + 0.125*log2e, scatter b,h,n,d)
//             1 -> K (RoPE, scatter b,h,n,d)
//             2 -> V (plain, TRANSPOSED store b,h,d,n)
__global__ __launch_bounds__(256,4)
void qkv_k(const float* xq, const float* xk, const float* xv,
           const float* Wq, const float* Wk, const float* Wv,
           u16* qo, u16* ko, u16* vo, const float2* tab)
{
  constexpr int BK = 32;
  __shared__ u16 lA[128][40];
  __shared__ u16 lB[128][40];
  const int tid  = threadIdx.x;
  const int lane = tid & 63;
  const int wid  = tid >> 6;
  const int wr = wid >> 1, wc = wid & 1;
  const int bm = blockIdx.x, bn = blockIdx.y;
  const int z  = blockIdx.z;           // wave-uniform mode
  const int arow0 = bm*128, brow0 = bn*128;

  const float* Af = (z==0) ? xq : (z==1) ? xk : xv;
  const float* W  = (z==0) ? Wq : (z==1) ? Wk : Wv;

  f32x4 acc[4][4];
  #pragma unroll
  for (int i=0;i<4;i++)
    #pragma unroll
    for (int j=0;j<4;j++) acc[i][j] = (f32x4){0.f,0.f,0.f,0.f};

  const int sr = tid >> 2;
  const int sc = tid & 3;

  float4 ra[2][2], rb[2][2];

  auto loadA = [&](int k0){
    #pragma unroll
    for (int s=0;s<2;s++){
      const float* p = Af + (size_t)(arow0 + sr + s*64)*KK + k0 + sc*8;
      ra[s][0] = *(const float4*)p;
      ra[s][1] = *(const float4*)(p+4);
    }
  };
  auto loadB = [&](int k0){
    #pragma unroll
    for (int s=0;s<2;s++){
      const float* p = W + (size_t)(brow0 + sr + s*64)*KK + k0 + sc*8;
      rb[s][0] = *(const float4*)p;
      rb[s][1] = *(const float4*)(p+4);
    }
  };

  loadA(0); loadB(0);

  for (int t=0; t<KK/BK; ++t){
    __syncthreads();
    *(uint4*)&lA[sr   ][sc*8] = pack8(ra[0][0], ra[0][1]);
    *(uint4*)&lA[sr+64][sc*8] = pack8(ra[1][0], ra[1][1]);
    *(uint4*)&lB[sr   ][sc*8] = pack8(rb[0][0], rb[0][1]);
    *(uint4*)&lB[sr+64][sc*8] = pack8(rb[1][0], rb[1][1]);
    __syncthreads();
    if (t+1 < KK/BK){ loadA((t+1)*BK); loadB((t+1)*BK); }

    bf16x8 af[4], bfr[4];
    const int g = lane >> 4, rr = lane & 15;
    #pragma unroll
    for (int i=0;i<4;i++) af[i]  = *(const bf16x8*)&lA[wr*64 + i*16 + rr][g*8];
    #pragma unroll
    for (int j=0;j<4;j++) bfr[j] = *(const bf16x8*)&lB[wc*64 + j*16 + rr][g*8];
    #pragma unroll
    for (int i=0;i<4;i++)
      #pragma unroll
      for (int j=0;j<4;j++)
        acc[i][j] = MFMA(af[i], bfr[j], acc[i][j]);
  }

  // epilogue (wave-uniform branch on z)
  if (z == 2){
    #pragma unroll
    for (int i=0;i<4;i++){
      #pragma unroll
      for (int j=0;j<4;j++){
        const int m0 = arow0 + wr*64 + i*16 + (lane>>4)*4;
        const int c  = brow0 + wc*64 + j*16 + (lane&15);
        const int pos = m0 & (SEQ-1);
        const int bidx = m0 >> 11;
        const int h = c >> 6, dd = c & 63;
        uint2 pk;
        pk.x = (u32)f2bf(acc[i][j][0]) | ((u32)f2bf(acc[i][j][1])<<16);
        pk.y = (u32)f2bf(acc[i][j][2]) | ((u32)f2bf(acc[i][j][3])<<16);
        *(uint2*)&vo[((size_t)(bidx*HEADS + h)*DH + dd)*SEQ + pos] = pk;
      }
    }
  } else {
    u16* outp = (z==0) ? qo : ko;
    const float scl = (z==0) ? 0.18033688011112042f : 1.0f; // 0.125*log2(e)
    #pragma unroll
    for (int i=0;i<4;i++){
      #pragma unroll
      for (int j=0;j<4;j++){
        #pragma unroll
        for (int r=0;r<4;r++){
          const int m = arow0 + wr*64 + i*16 + (lane>>4)*4 + r;
          const int c = brow0 + wc*64 + j*16 + (lane&15);
          float v = acc[i][j][r];
          const int pos = m & (SEQ-1);
          const int bidx = m >> 11;
          const int h = c >> 6, dd = c & 63;
          float2 cs = tab[pos*32 + (dd>>1)];
          float vp = __shfl_xor(v, 1);
          float o = ((dd&1)==0) ? (v*cs.x - vp*cs.y) : (v*cs.x + vp*cs.y);
          o *= scl;
          outp[(((size_t)(bidx*HEADS + h))*SEQ + pos)*DH + dd] = f2bf(o);
        }
      }
    }
  }
}

// ---------------- out-projection GEMM (R17-proven: 4 blocks/CU) --------------
__global__ __launch_bounds__(256,4)
void gemm_out_k(const u16* Ab, const float* W, float* outp)
{
  constexpr int BK = 32;
  __shared__ u16 lA[128][40];
  __shared__ u16 lB[128][40];
  const int tid  = threadIdx.x;
  const int lane = tid & 63;
  const int wid  = tid >> 6;
  const int wr = wid >> 1, wc = wid & 1;
  const int bm = blockIdx.x, bn = blockIdx.y;
  const int arow0 = bm*128, brow0 = bn*128;

  f32x4 acc[4][4];
  #pragma unroll
  for (int i=0;i<4;i++)
    #pragma unroll
    for (int j=0;j<4;j++) acc[i][j] = (f32x4){0.f,0.f,0.f,0.f};

  const int sr = tid >> 2;
  const int sc = tid & 3;

  float4 rb[2][2];
  uint4  rab[2];

  auto loadA = [&](int k0){
    const u16* p = Ab + (size_t)(arow0 + (tid>>1))*KK + k0 + (tid&1)*16;
    rab[0] = *(const uint4*)(p);
    rab[1] = *(const uint4*)(p+8);
  };
  auto loadB = [&](int k0){
    #pragma unroll
    for (int s=0;s<2;s++){
      const float* p = W + (size_t)(brow0 + sr + s*64)*KK + k0 + sc*8;
      rb[s][0] = *(const float4*)p;
      rb[s][1] = *(const float4*)(p+4);
    }
  };

  loadA(0); loadB(0);

  for (int t=0; t<KK/BK; ++t){
    __syncthreads();
    *(uint4*)&lA[tid>>1][(tid&1)*16 + 0] = rab[0];
    *(uint4*)&lA[tid>>1][(tid&1)*16 + 8] = rab[1];
    *(uint4*)&lB[sr   ][sc*8] = pack8(rb[0][0], rb[0][1]);
    *(uint4*)&lB[sr+64][sc*8] = pack8(rb[1][0], rb[1][1]);
    __syncthreads();
    if (t+1 < KK/BK){ loadA((t+1)*BK); loadB((t+1)*BK); }

    bf16x8 af[4], bfr[4];
    const int g = lane >> 4, rr = lane & 15;
    #pragma unroll
    for (int i=0;i<4;i++) af[i]  = *(const bf16x8*)&lA[wr*64 + i*16 + rr][g*8];
    #pragma unroll
    for (int j=0;j<4;j++) bfr[j] = *(const bf16x8*)&lB[wc*64 + j*16 + rr][g*8];
    #pragma unroll
    for (int i=0;i<4;i++)
      #pragma unroll
      for (int j=0;j<4;j++)
        acc[i][j] = MFMA(af[i], bfr[j], acc[i][j]);
  }

  #pragma unroll
  for (int i=0;i<4;i++)
    #pragma unroll
    for (int j=0;j<4;j++)
      #pragma unroll
      for (int r=0;r<4;r++){
        const int m = arow0 + wr*64 + i*16 + (lane>>4)*4 + r;
        const int c = brow0 + wc*64 + j*16 + (lane&15);
        outp[(size_t)m*HID + c] = acc[i][j][r];
      }
}

// ---------------- flash attention (R12 structure, isolated occ-4 test) -------
__global__ __launch_bounds__(256,4)
void attn_k(const u16* q, const u16* kkp, const u16* vtp, u16* o,
            const float* bias_g, const u32* flagbits, const int* pcaus, const int* psp)
{
  const int tid = threadIdx.x, lane = tid & 63, wid = tid >> 6;
  const int NQT = SEQ/64;
  const int wg = blockIdx.x;
  const int xcd = wg & 7, kk2 = wg >> 3;
  const int bh = xcd*8 + (kk2 >> 4);
  const int qpair = kk2 & 15;
  const int q0lo = qpair*64;
  const int q0hi = (NQT-1-qpair)*64;
  const int b = bh >> 4;
  const int causal = *pcaus, sp = *psp;

  __shared__ u16 lK[2][64*64];
  __shared__ u16 lV[2][64*64];

  const size_t hbase = (size_t)bh * SEQ * DH;
  const int h = lane >> 5, ln31 = lane & 31, ln7 = lane & 7;

  const int i0w = (wid < 2) ? (q0lo + wid*32) : (q0hi + (wid-2)*32);
  const int myq = i0w + ln31;
  const u32 fbits = flagbits[b];

  bf16x8 qf[4];
  {
    const u16* qr = q + hbase + (size_t)myq*DH;
    #pragma unroll
    for (int s=0;s<4;s++) qf[s] = *(const bf16x8*)(qr + 16*s + 8*h);
  }

  int swz[4];
  #pragma unroll
  for (int s=0;s<4;s++) swz[s] = ((2*s + h) ^ ln7) * 8;

  f32x16 oac[2];
  #pragma unroll
  for (int t=0;t<16;t++){ oac[0][t] = 0.f; oac[1][t] = 0.f; }
  float mrun = -__builtin_inff(), lrun = 0.f;

  int jmax = causal ? ((q0hi+63 > sp-1) ? q0hi+63 : sp-1) : (SEQ-1);
  if (jmax > SEQ-1) jmax = SEQ-1;
  const int ntile = (jmax >> 6) + 1;

  uint4 kr0, kr1, vr0, vr1;
  const int srow = tid >> 2;
  const int sg   = (tid & 3)*2;
  const int sw   = srow & 7;
  auto gload = [&](int kt){
    const int j0 = kt*64;
    const u16* pk = kkp + hbase + (size_t)(j0+srow)*DH + sg*8;
    kr0 = *(const uint4*)pk;  kr1 = *(const uint4*)(pk+8);
    const u16* pv = vtp + hbase + (size_t)srow*SEQ + j0 + sg*8;
    vr0 = *(const uint4*)pv;  vr1 = *(const uint4*)(pv+8);
  };
  auto lwrite = [&](int buf){
    *(uint4*)&lK[buf][srow*64 + ((sg    ^sw)*8)] = kr0;
    *(uint4*)&lK[buf][srow*64 + (((sg+1)^sw)*8)] = kr1;
    *(uint4*)&lV[buf][srow*64 + ((sg    ^sw)*8)] = vr0;
    *(uint4*)&lV[buf][srow*64 + (((sg+1)^sw)*8)] = vr1;
  };

  gload(0);
  lwrite(0);
  int cur = 0;

  for (int kt=0; kt<ntile; ++kt){
    const int j0 = kt*64;
    __syncthreads();
    if (kt+1 < ntile) gload(kt+1);

    const bool active = !(causal && j0 >= sp && j0 > i0w+31);
    if (active){
      const u16* Kb = lK[cur];
      const u16* Vb = lV[cur];

      f32x16 sA, sB;
      #pragma unroll
      for (int t=0;t<16;t++){ sA[t] = 0.f; sB[t] = 0.f; }
      __builtin_amdgcn_s_setprio(1);
      #pragma unroll
      for (int s=0;s<4;s++){
        bf16x8 k0 = *(const bf16x8*)&Kb[ ln31    *64 + swz[s]];
        bf16x8 k1 = *(const bf16x8*)&Kb[(32+ln31)*64 + swz[s]];
        sA = MFMA32(k0, qf[s], sA);
        sB = MFMA32(k1, qf[s], sB);
      }
      __builtin_amdgcn_s_setprio(0);

      float sv[32];
      #pragma unroll
      for (int t=0;t<16;t++){ sv[t] = sA[t]; sv[16+t] = sB[t]; }

      if ((fbits >> kt) & 1u){
        #pragma unroll
        for (int t=0;t<32;t++){
          const int rt = ((t&3) + 8*((t&15)>>2) + 4*h) + 32*(t>>4);
          sv[t] += bias_g[b*SEQ + j0 + rt];
        }
      }
      const bool needmask = causal && !((j0+63 < sp) || (i0w >= sp && j0+63 <= i0w));
      if (needmask){
        #pragma unroll
        for (int t=0;t<32;t++){
          const int jj = j0 + ((t&3) + 8*((t&15)>>2) + 4*h) + 32*(t>>4);
          const bool allow = (jj < sp) || (myq >= sp && myq >= jj);
          sv[t] = allow ? sv[t] : -__builtin_inff();
        }
      }

      float m8[8];
      #pragma unroll
      for (int t=0;t<8;t++)
        m8[t] = fmaxf(fmaxf(sv[t], sv[t+8]), fmaxf(sv[t+16], sv[t+24]));
      float m4a = fmaxf(fmaxf(m8[0],m8[1]), fmaxf(m8[2],m8[3]));
      float m4b = fmaxf(fmaxf(m8[4],m8[5]), fmaxf(m8[6],m8[7]));
      float pmax = fmaxf(m4a, m4b);
      pmax = fmaxf(pmax, __shfl_xor(pmax, 32));
      const float mnew = fmaxf(mrun, pmax);
      if (!__all(pmax - mrun <= 8.f)){
        const float fac = exp2f(mrun - mnew);
        mrun = mnew;
        lrun *= fac;
        oac[0] *= fac;
        oac[1] *= fac;
      }
      float p[32];
      #pragma unroll
      for (int t=0;t<32;t++) p[t] = exp2f(sv[t] - mrun);
      float a16[16];
      #pragma unroll
      for (int t=0;t<16;t++) a16[t] = p[t] + p[t+16];
      float a8[8];
      #pragma unroll
      for (int t=0;t<8;t++) a8[t] = a16[t] + a16[t+8];
      float rs = ((a8[0]+a8[1]) + (a8[2]+a8[3])) + ((a8[4]+a8[5]) + (a8[6]+a8[7]));
      rs += __shfl_xor(rs, 32);
      lrun += rs;

      u32 w[16];
      #pragma unroll
      for (int u=0;u<16;u++){
        asm("v_cvt_pk_bf16_f32 %0, %1, %2" : "=v"(w[u]) : "v"(p[2*u]), "v"(p[2*u+1]));
      }

      __builtin_amdgcn_s_setprio(1);
      #pragma unroll
      for (int st=0; st<4; ++st){
        const int base = 8*(st>>1) + 4*(st&1);
        u32 x0 = h ? w[base+0] : w[base+2];
        u32 x1 = h ? w[base+1] : w[base+3];
        u32 r0 = (u32)__shfl_xor((int)x0, 32);
        u32 r1 = (u32)__shfl_xor((int)x1, 32);
        uint4 fw;
        fw.x = h ? r0 : w[base+0];
        fw.y = h ? r1 : w[base+1];
        fw.z = h ? w[base+2] : r0;
        fw.w = h ? w[base+3] : r1;
        bf16x8 pf = __builtin_bit_cast(bf16x8, fw);
        #pragma unroll
        for (int dt=0; dt<2; ++dt){
          bf16x8 vf = *(const bf16x8*)&Vb[(dt*32+ln31)*64 + swz[st]];
          oac[dt] = MFMA32(vf, pf, oac[dt]);
        }
      }
      __builtin_amdgcn_s_setprio(0);
    }

    if (kt+1 < ntile) lwrite(cur^1);
    cur ^= 1;
  }

  const float inv = 1.f / lrun;
  u16* orow = o + ((size_t)(b*SEQ) + myq)*HID + (size_t)(bh&15)*DH;
  #pragma unroll
  for (int dt=0; dt<2; ++dt)
    #pragma unroll
    for (int a=0; a<4; ++a){
      const int d0 = dt*32 + 8*a + 4*h;
      uint2 pk;
      pk.x = (u32)f2bf(oac[dt][4*a+0]*inv) | ((u32)f2bf(oac[dt][4*a+1]*inv)<<16);
      pk.y = (u32)f2bf(oac[dt][4*a+2]*inv) | ((u32)f2bf(oac[dt][4*a+3]*inv)<<16);
      *(uint2*)(orow + d0) = pk;
    }
}

// -----------------------------------------------------------------------------
extern "C" void kernel_launch(void* const* d_in, const int* in_sizes, int n_in,
                              void* d_out, int out_size, void* d_ws, size_t ws_size,
                              hipStream_t stream)
{
  const float* x_q = (const float*)d_in[0];
  const float* x_k = (const float*)d_in[1];
  const float* x_v = (const float*)d_in[2];
  const float* W_q = (const float*)d_in[3];
  const float* W_k = (const float*)d_in[4];
  const float* W_v = (const float*)d_in[5];
  const float* W_o = (const float*)d_in[6];
  const int*   pm  = (const int*)d_in[7];
  const int* caus = (const int*)d_in[8];
  const int* sp   = (const int*)d_in[9];

  char* ws = (char*)d_ws;
  float2* tab   = (float2*)ws;                      // 512 KiB
  u16*  v_ws    = (u16*)(ws + (1u<<20));            // 16 MiB (V^T: b,h,d,n)
  u16*  o_ws    = (u16*)(ws + (17u<<20));           // 16 MiB
  float* bias   = (float*)(ws + (33u<<20));         // 32 KiB
  u32*  flagb   = (u32*)(ws + (33u<<20) + (1u<<15));
  // q,k scratch live inside d_out (32 MiB); stream order makes this race-free
  // (structure proven passing in rounds 2-6, 11, 12, 14-18).
  u16* q_ws = (u16*)d_out;
  u16* k_ws = ((u16*)d_out) + (size_t)MM*HID;

  rope_tab_kernel<<<SEQ*32/256, 256, 0, stream>>>(tab);
  mask_bias_kernel<<<1, 1024, 0, stream>>>(pm, bias, flagb, BB*SEQ);

  dim3 gq(MM/128, HID/128, 3);
  qkv_k<<<gq, 256, 0, stream>>>(x_q, x_k, x_v, W_q, W_k, W_v,
                                q_ws, k_ws, v_ws, tab);

  attn_k<<<1024, 256, 0, stream>>>(q_ws, k_ws, v_ws, o_ws, bias, flagb, caus, sp);

  dim3 gg(MM/128, HID/128);
  gemm_out_k<<<gg, 256, 0, stream>>>(o_ws, W_o, (float*)d_out);
}

// Round 20
// 272.134 us; speedup vs baseline: 2.5482x; 1.0117x over previous
//
#include <hip/hip_runtime.h>
#include <hip/hip_bf16.h>
#include <math.h>

#define BB 4
#define SEQ 2048
#define HEADS 16
#define DH 64
#define HID 1024
#define MM (BB*SEQ)
#define KK HID

typedef __attribute__((ext_vector_type(8))) short bf16x8;
typedef __attribute__((ext_vector_type(4))) float f32x4;
typedef __attribute__((ext_vector_type(16))) float f32x16;
typedef unsigned short u16;
typedef unsigned int u32;

__device__ __forceinline__ u16 f2bf(float f){
  u32 u = __builtin_bit_cast(u32, f);
  u += 0x7fffu + ((u>>16)&1u);
  return (u16)(u>>16);
}

// 8x f32 -> packed bf16, integer RNE form (R12-proven)
__device__ __forceinline__ uint4 pack8(const float4 a, const float4 b){
  uint4 r;
  r.x = (u32)f2bf(a.x) | ((u32)f2bf(a.y)<<16);
  r.y = (u32)f2bf(a.z) | ((u32)f2bf(a.w)<<16);
  r.z = (u32)f2bf(b.x) | ((u32)f2bf(b.y)<<16);
  r.w = (u32)f2bf(b.z) | ((u32)f2bf(b.w)<<16);
  return r;
}

#define MFMA(a,b,c)   __builtin_amdgcn_mfma_f32_16x16x32_bf16(a,b,c,0,0,0)
#define MFMA32(a,b,c) __builtin_amdgcn_mfma_f32_32x32x16_bf16(a,b,c,0,0,0)

// ---------------- RoPE cos/sin table: [pos][p] float2, p = 0..31 -------------
__global__ void rope_tab_kernel(float2* tab){
  int idx = blockIdx.x*256 + threadIdx.x;
  if (idx >= SEQ*32) return;
  int pos = idx >> 5, p = idx & 31;
  double inv = exp2(-(double)p * (13.287712379549449/32.0)); // 10000^(-p/32)
  double a = (double)pos * inv;
  tab[idx] = make_float2((float)cos(a), (float)sin(a));
}

// ---------------- padding-mask normalizer (int32 or uint8 robust) ------------
__global__ __launch_bounds__(1024)
void mask_bias_kernel(const int* pm, float* bias, u32* flagbits, int nelem){
  __shared__ int flag;
  if (threadIdx.x == 0) flag = 0;
  if (threadIdx.x < BB) flagbits[threadIdx.x] = 0u;
  __syncthreads();
  int bad = 0;
  for (int i = threadIdx.x; i < nelem/4; i += 1024){
    u32 v = ((const u32*)pm)[i];
    if (v > 1u) bad = 1;
  }
  if (bad) atomicOr(&flag, 1);
  __syncthreads();
  const int u8mode = flag;
  for (int i = threadIdx.x; i < nelem; i += 1024){
    int v = u8mode ? (int)((const unsigned char*)pm)[i] : pm[i];
    bias[i] = v ? 0.f : -__builtin_inff();
    if (!v) atomicOr(&flagbits[i>>11], 1u << ((i & (SEQ-1)) >> 6));
  }
}

// ---------------- fused QKV GEMM (R17-proven: 4 blocks/CU) -------------------
// blockIdx.z: 0 -> Q (RoPE + 0.125*log2e, scatter b,h,n,d)
//             1 -> K (RoPE, scatter b,h,n,d)
//             2 -> V (plain, TRANSPOSED store b,h,d,n)
__global__ __launch_bounds__(256,4)
void qkv_k(const float* xq, const float* xk, const float* xv,
           const float* Wq, const float* Wk, const float* Wv,
           u16* qo, u16* ko, u16* vo, const float2* tab)
{
  constexpr int BK = 32;
  __shared__ u16 lA[128][40];
  __shared__ u16 lB[128][40];
  const int tid  = threadIdx.x;
  const int lane = tid & 63;
  const int wid  = tid >> 6;
  const int wr = wid >> 1, wc = wid & 1;
  const int bm = blockIdx.x, bn = blockIdx.y;
  const int z  = blockIdx.z;           // wave-uniform mode
  const int arow0 = bm*128, brow0 = bn*128;

  const float* Af = (z==0) ? xq : (z==1) ? xk : xv;
  const float* W  = (z==0) ? Wq : (z==1) ? Wk : Wv;

  f32x4 acc[4][4];
  #pragma unroll
  for (int i=0;i<4;i++)
    #pragma unroll
    for (int j=0;j<4;j++) acc[i][j] = (f32x4){0.f,0.f,0.f,0.f};

  const int sr = tid >> 2;
  const int sc = tid & 3;

  float4 ra[2][2], rb[2][2];

  auto loadA = [&](int k0){
    #pragma unroll
    for (int s=0;s<2;s++){
      const float* p = Af + (size_t)(arow0 + sr + s*64)*KK + k0 + sc*8;
      ra[s][0] = *(const float4*)p;
      ra[s][1] = *(const float4*)(p+4);
    }
  };
  auto loadB = [&](int k0){
    #pragma unroll
    for (int s=0;s<2;s++){
      const float* p = W + (size_t)(brow0 + sr + s*64)*KK + k0 + sc*8;
      rb[s][0] = *(const float4*)p;
      rb[s][1] = *(const float4*)(p+4);
    }
  };

  loadA(0); loadB(0);

  for (int t=0; t<KK/BK; ++t){
    __syncthreads();
    *(uint4*)&lA[sr   ][sc*8] = pack8(ra[0][0], ra[0][1]);
    *(uint4*)&lA[sr+64][sc*8] = pack8(ra[1][0], ra[1][1]);
    *(uint4*)&lB[sr   ][sc*8] = pack8(rb[0][0], rb[0][1]);
    *(uint4*)&lB[sr+64][sc*8] = pack8(rb[1][0], rb[1][1]);
    __syncthreads();
    if (t+1 < KK/BK){ loadA((t+1)*BK); loadB((t+1)*BK); }

    bf16x8 af[4], bfr[4];
    const int g = lane >> 4, rr = lane & 15;
    #pragma unroll
    for (int i=0;i<4;i++) af[i]  = *(const bf16x8*)&lA[wr*64 + i*16 + rr][g*8];
    #pragma unroll
    for (int j=0;j<4;j++) bfr[j] = *(const bf16x8*)&lB[wc*64 + j*16 + rr][g*8];
    #pragma unroll
    for (int i=0;i<4;i++)
      #pragma unroll
      for (int j=0;j<4;j++)
        acc[i][j] = MFMA(af[i], bfr[j], acc[i][j]);
  }

  // epilogue (wave-uniform branch on z)
  if (z == 2){
    #pragma unroll
    for (int i=0;i<4;i++){
      #pragma unroll
      for (int j=0;j<4;j++){
        const int m0 = arow0 + wr*64 + i*16 + (lane>>4)*4;
        const int c  = brow0 + wc*64 + j*16 + (lane&15);
        const int pos = m0 & (SEQ-1);
        const int bidx = m0 >> 11;
        const int h = c >> 6, dd = c & 63;
        uint2 pk;
        pk.x = (u32)f2bf(acc[i][j][0]) | ((u32)f2bf(acc[i][j][1])<<16);
        pk.y = (u32)f2bf(acc[i][j][2]) | ((u32)f2bf(acc[i][j][3])<<16);
        *(uint2*)&vo[((size_t)(bidx*HEADS + h)*DH + dd)*SEQ + pos] = pk;
      }
    }
  } else {
    u16* outp = (z==0) ? qo : ko;
    const float scl = (z==0) ? 0.18033688011112042f : 1.0f; // 0.125*log2(e)
    #pragma unroll
    for (int i=0;i<4;i++){
      #pragma unroll
      for (int j=0;j<4;j++){
        #pragma unroll
        for (int r=0;r<4;r++){
          const int m = arow0 + wr*64 + i*16 + (lane>>4)*4 + r;
          const int c = brow0 + wc*64 + j*16 + (lane&15);
          float v = acc[i][j][r];
          const int pos = m & (SEQ-1);
          const int bidx = m >> 11;
          const int h = c >> 6, dd = c & 63;
          float2 cs = tab[pos*32 + (dd>>1)];
          float vp = __shfl_xor(v, 1);
          float o = ((dd&1)==0) ? (v*cs.x - vp*cs.y) : (v*cs.x + vp*cs.y);
          o *= scl;
          outp[(((size_t)(bidx*HEADS + h))*SEQ + pos)*DH + dd] = f2bf(o);
        }
      }
    }
  }
}

// ---------------- out-projection GEMM (R17-proven: 4 blocks/CU) --------------
__global__ __launch_bounds__(256,4)
void gemm_out_k(const u16* Ab, const float* W, float* outp)
{
  constexpr int BK = 32;
  __shared__ u16 lA[128][40];
  __shared__ u16 lB[128][40];
  const int tid  = threadIdx.x;
  const int lane = tid & 63;
  const int wid  = tid >> 6;
  const int wr = wid >> 1, wc = wid & 1;
  const int bm = blockIdx.x, bn = blockIdx.y;
  const int arow0 = bm*128, brow0 = bn*128;

  f32x4 acc[4][4];
  #pragma unroll
  for (int i=0;i<4;i++)
    #pragma unroll
    for (int j=0;j<4;j++) acc[i][j] = (f32x4){0.f,0.f,0.f,0.f};

  const int sr = tid >> 2;
  const int sc = tid & 3;

  float4 rb[2][2];
  uint4  rab[2];

  auto loadA = [&](int k0){
    const u16* p = Ab + (size_t)(arow0 + (tid>>1))*KK + k0 + (tid&1)*16;
    rab[0] = *(const uint4*)(p);
    rab[1] = *(const uint4*)(p+8);
  };
  auto loadB = [&](int k0){
    #pragma unroll
    for (int s=0;s<2;s++){
      const float* p = W + (size_t)(brow0 + sr + s*64)*KK + k0 + sc*8;
      rb[s][0] = *(const float4*)p;
      rb[s][1] = *(const float4*)(p+4);
    }
  };

  loadA(0); loadB(0);

  for (int t=0; t<KK/BK; ++t){
    __syncthreads();
    *(uint4*)&lA[tid>>1][(tid&1)*16 + 0] = rab[0];
    *(uint4*)&lA[tid>>1][(tid&1)*16 + 8] = rab[1];
    *(uint4*)&lB[sr   ][sc*8] = pack8(rb[0][0], rb[0][1]);
    *(uint4*)&lB[sr+64][sc*8] = pack8(rb[1][0], rb[1][1]);
    __syncthreads();
    if (t+1 < KK/BK){ loadA((t+1)*BK); loadB((t+1)*BK); }

    bf16x8 af[4], bfr[4];
    const int g = lane >> 4, rr = lane & 15;
    #pragma unroll
    for (int i=0;i<4;i++) af[i]  = *(const bf16x8*)&lA[wr*64 + i*16 + rr][g*8];
    #pragma unroll
    for (int j=0;j<4;j++) bfr[j] = *(const bf16x8*)&lB[wc*64 + j*16 + rr][g*8];
    #pragma unroll
    for (int i=0;i<4;i++)
      #pragma unroll
      for (int j=0;j<4;j++)
        acc[i][j] = MFMA(af[i], bfr[j], acc[i][j]);
  }

  #pragma unroll
  for (int i=0;i<4;i++)
    #pragma unroll
    for (int j=0;j<4;j++)
      #pragma unroll
      for (int r=0;r<4;r++){
        const int m = arow0 + wr*64 + i*16 + (lane>>4)*4 + r;
        const int c = brow0 + wc*64 + j*16 + (lane&15);
        outp[(size_t)m*HID + c] = acc[i][j][r];
      }
}

// ---------------- flash attention (R17-proven: 3 blocks/CU) ------------------
__global__ __launch_bounds__(256,3)
void attn_k(const u16* q, const u16* kkp, const u16* vtp, u16* o,
            const float* bias_g, const u32* flagbits, const int* pcaus, const int* psp)
{
  const int tid = threadIdx.x, lane = tid & 63, wid = tid >> 6;
  const int NQT = SEQ/64;
  const int wg = blockIdx.x;
  const int xcd = wg & 7, kk2 = wg >> 3;
  const int bh = xcd*8 + (kk2 >> 4);
  const int qpair = kk2 & 15;
  const int q0lo = qpair*64;
  const int q0hi = (NQT-1-qpair)*64;
  const int b = bh >> 4;
  const int causal = *pcaus, sp = *psp;

  __shared__ u16 lK[2][64*64];
  __shared__ u16 lV[2][64*64];

  const size_t hbase = (size_t)bh * SEQ * DH;
  const int h = lane >> 5, ln31 = lane & 31, ln7 = lane & 7;

  const int i0w = (wid < 2) ? (q0lo + wid*32) : (q0hi + (wid-2)*32);
  const int myq = i0w + ln31;
  const u32 fbits = flagbits[b];

  bf16x8 qf[4];
  {
    const u16* qr = q + hbase + (size_t)myq*DH;
    #pragma unroll
    for (int s=0;s<4;s++) qf[s] = *(const bf16x8*)(qr + 16*s + 8*h);
  }

  int swz[4];
  #pragma unroll
  for (int s=0;s<4;s++) swz[s] = ((2*s + h) ^ ln7) * 8;

  f32x16 oac[2];
  #pragma unroll
  for (int t=0;t<16;t++){ oac[0][t] = 0.f; oac[1][t] = 0.f; }
  float mrun = -__builtin_inff(), lrun = 0.f;

  int jmax = causal ? ((q0hi+63 > sp-1) ? q0hi+63 : sp-1) : (SEQ-1);
  if (jmax > SEQ-1) jmax = SEQ-1;
  const int ntile = (jmax >> 6) + 1;

  uint4 kr0, kr1, vr0, vr1;
  const int srow = tid >> 2;
  const int sg   = (tid & 3)*2;
  const int sw   = srow & 7;
  auto gload = [&](int kt){
    const int j0 = kt*64;
    const u16* pk = kkp + hbase + (size_t)(j0+srow)*DH + sg*8;
    kr0 = *(const uint4*)pk;  kr1 = *(const uint4*)(pk+8);
    const u16* pv = vtp + hbase + (size_t)srow*SEQ + j0 + sg*8;
    vr0 = *(const uint4*)pv;  vr1 = *(const uint4*)(pv+8);
  };
  auto lwrite = [&](int buf){
    *(uint4*)&lK[buf][srow*64 + ((sg    ^sw)*8)] = kr0;
    *(uint4*)&lK[buf][srow*64 + (((sg+1)^sw)*8)] = kr1;
    *(uint4*)&lV[buf][srow*64 + ((sg    ^sw)*8)] = vr0;
    *(uint4*)&lV[buf][srow*64 + (((sg+1)^sw)*8)] = vr1;
  };

  gload(0);
  lwrite(0);
  int cur = 0;

  for (int kt=0; kt<ntile; ++kt){
    const int j0 = kt*64;
    __syncthreads();
    if (kt+1 < ntile) gload(kt+1);

    const bool active = !(causal && j0 >= sp && j0 > i0w+31);
    if (active){
      const u16* Kb = lK[cur];
      const u16* Vb = lV[cur];

      f32x16 sA, sB;
      #pragma unroll
      for (int t=0;t<16;t++){ sA[t] = 0.f; sB[t] = 0.f; }
      __builtin_amdgcn_s_setprio(1);
      #pragma unroll
      for (int s=0;s<4;s++){
        bf16x8 k0 = *(const bf16x8*)&Kb[ ln31    *64 + swz[s]];
        bf16x8 k1 = *(const bf16x8*)&Kb[(32+ln31)*64 + swz[s]];
        sA = MFMA32(k0, qf[s], sA);
        sB = MFMA32(k1, qf[s], sB);
      }
      __builtin_amdgcn_s_setprio(0);

      float sv[32];
      #pragma unroll
      for (int t=0;t<16;t++){ sv[t] = sA[t]; sv[16+t] = sB[t]; }

      if ((fbits >> kt) & 1u){
        #pragma unroll
        for (int t=0;t<32;t++){
          const int rt = ((t&3) + 8*((t&15)>>2) + 4*h) + 32*(t>>4);
          sv[t] += bias_g[b*SEQ + j0 + rt];
        }
      }
      const bool needmask = causal && !((j0+63 < sp) || (i0w >= sp && j0+63 <= i0w));
      if (needmask){
        #pragma unroll
        for (int t=0;t<32;t++){
          const int jj = j0 + ((t&3) + 8*((t&15)>>2) + 4*h) + 32*(t>>4);
          const bool allow = (jj < sp) || (myq >= sp && myq >= jj);
          sv[t] = allow ? sv[t] : -__builtin_inff();
        }
      }

      float m8[8];
      #pragma unroll
      for (int t=0;t<8;t++)
        m8[t] = fmaxf(fmaxf(sv[t], sv[t+8]), fmaxf(sv[t+16], sv[t+24]));
      float m4a = fmaxf(fmaxf(m8[0],m8[1]), fmaxf(m8[2],m8[3]));
      float m4b = fmaxf(fmaxf(m8[4],m8[5]), fmaxf(m8[6],m8[7]));
      float pmax = fmaxf(m4a, m4b);
      pmax = fmaxf(pmax, __shfl_xor(pmax, 32));
      const float mnew = fmaxf(mrun, pmax);
      if (!__all(pmax - mrun <= 8.f)){
        const float fac = exp2f(mrun - mnew);
        mrun = mnew;
        lrun *= fac;
        oac[0] *= fac;
        oac[1] *= fac;
      }
      float p[32];
      #pragma unroll
      for (int t=0;t<32;t++) p[t] = exp2f(sv[t] - mrun);
      float a16[16];
      #pragma unroll
      for (int t=0;t<16;t++) a16[t] = p[t] + p[t+16];
      float a8[8];
      #pragma unroll
      for (int t=0;t<8;t++) a8[t] = a16[t] + a16[t+8];
      float rs = ((a8[0]+a8[1]) + (a8[2]+a8[3])) + ((a8[4]+a8[5]) + (a8[6]+a8[7]));
      rs += __shfl_xor(rs, 32);
      lrun += rs;

      u32 w[16];
      #pragma unroll
      for (int u=0;u<16;u++){
        asm("v_cvt_pk_bf16_f32 %0, %1, %2" : "=v"(w[u]) : "v"(p[2*u]), "v"(p[2*u+1]));
      }

      __builtin_amdgcn_s_setprio(1);
      #pragma unroll
      for (int st=0; st<4; ++st){
        const int base = 8*(st>>1) + 4*(st&1);
        u32 x0 = h ? w[base+0] : w[base+2];
        u32 x1 = h ? w[base+1] : w[base+3];
        u32 r0 = (u32)__shfl_xor((int)x0, 32);
        u32 r1 = (u32)__shfl_xor((int)x1, 32);
        uint4 fw;
        fw.x = h ? r0 : w[base+0];
        fw.y = h ? r1 : w[base+1];
        fw.z = h ? w[base+2] : r0;
        fw.w = h ? w[base+3] : r1;
        bf16x8 pf = __builtin_bit_cast(bf16x8, fw);
        #pragma unroll
        for (int dt=0; dt<2; ++dt){
          bf16x8 vf = *(const bf16x8*)&Vb[(dt*32+ln31)*64 + swz[st]];
          oac[dt] = MFMA32(vf, pf, oac[dt]);
        }
      }
      __builtin_amdgcn_s_setprio(0);
    }

    if (kt+1 < ntile) lwrite(cur^1);
    cur ^= 1;
  }

  const float inv = 1.f / lrun;
  u16* orow = o + ((size_t)(b*SEQ) + myq)*HID + (size_t)(bh&15)*DH;
  #pragma unroll
  for (int dt=0; dt<2; ++dt)
    #pragma unroll
    for (int a=0; a<4; ++a){
      const int d0 = dt*32 + 8*a + 4*h;
      uint2 pk;
      pk.x = (u32)f2bf(oac[dt][4*a+0]*inv) | ((u32)f2bf(oac[dt][4*a+1]*inv)<<16);
      pk.y = (u32)f2bf(oac[dt][4*a+2]*inv) | ((u32)f2bf(oac[dt][4*a+3]*inv)<<16);
      *(uint2*)(orow + d0) = pk;
    }
}

// -----------------------------------------------------------------------------
extern "C" void kernel_launch(void* const* d_in, const int* in_sizes, int n_in,
                              void* d_out, int out_size, void* d_ws, size_t ws_size,
                              hipStream_t stream)
{
  const float* x_q = (const float*)d_in[0];
  const float* x_k = (const float*)d_in[1];
  const float* x_v = (const float*)d_in[2];
  const float* W_q = (const float*)d_in[3];
  const float* W_k = (const float*)d_in[4];
  const float* W_v = (const float*)d_in[5];
  const float* W_o = (const float*)d_in[6];
  const int*   pm  = (const int*)d_in[7];
  const int* caus = (const int*)d_in[8];
  const int* sp   = (const int*)d_in[9];

  char* ws = (char*)d_ws;
  float2* tab   = (float2*)ws;                      // 512 KiB
  u16*  v_ws    = (u16*)(ws + (1u<<20));            // 16 MiB (V^T: b,h,d,n)
  u16*  o_ws    = (u16*)(ws + (17u<<20));           // 16 MiB
  float* bias   = (float*)(ws + (33u<<20));         // 32 KiB
  u32*  flagb   = (u32*)(ws + (33u<<20) + (1u<<15));
  // q,k scratch live inside d_out (32 MiB); stream order makes this race-free
  // (structure proven passing in rounds 2-6, 11, 12, 14-19).
  u16* q_ws = (u16*)d_out;
  u16* k_ws = ((u16*)d_out) + (size_t)MM*HID;

  rope_tab_kernel<<<SEQ*32/256, 256, 0, stream>>>(tab);
  mask_bias_kernel<<<1, 1024, 0, stream>>>(pm, bias, flagb, BB*SEQ);

  dim3 gq(MM/128, HID/128, 3);
  qkv_k<<<gq, 256, 0, stream>>>(x_q, x_k, x_v, W_q, W_k, W_v,
                                q_ws, k_ws, v_ws, tab);

  attn_k<<<1024, 256, 0, stream>>>(q_ws, k_ws, v_ws, o_ws, bias, flagb, caus, sp);

  dim3 gg(MM/128, HID/128);
  gemm_out_k<<<gg, 256, 0, stream>>>(o_ws, W_o, (float*)d_out);
}